// Round 10
// baseline (6281.332 us; speedup 1.0000x reference)
//
#include <hip/hip_runtime.h>
#include <hip/hip_bf16.h>

// Problem constants
#define BB   128
#define SS   100
#define WW   12
#define EE   256
#define MM   512
#define VV   10000
#define GP   0.1f
#define GN   0.1f
#define EPSB 1e-5f
#define EPSL 1e-5f

typedef float f32x4 __attribute__((ext_vector_type(4)));

// Workspace layout (floats), total 47417344 floats = 190 MB.
// m occupies [0, 33554432); semb and vbuf ALIAS its head — they are dead
// before k_scan writes m (stream-ordered), which also keeps ws small.
// NOTE (r4 post-mortem): m cannot live in registers — 1 MiB/block vs 512 KiB
// CU register file (regsPerBlock=131072 => 128 VGPR cap at 1024 thr) — nor in
// LDS (160 KiB). Global+L3 is the only home for m.
static constexpr size_t OFF_M    = 0;                        // 128*512*512
static constexpr size_t OFF_SEMB = 0;                        // 12800*256 (alias, dead pre-scan)
static constexpr size_t OFF_V    = 3276800;                  // 12800*512 (alias, dead pre-scan)
static constexpr size_t OFF_QEMB = 33554432;                 // 128*256
static constexpr size_t OFF_STAT = OFF_QEMB + 32768;         // 8*256
static constexpr size_t OFF_K    = OFF_STAT + 2048;          // 12800*512 (becomes kn in-place)
static constexpr size_t OFF_V2P  = OFF_K + 6553600;          // 12800*512
static constexpr size_t OFF_W2T  = OFF_V2P + 6553600;        // 512*512
static constexpr size_t OFF_RT   = OFF_W2T + 262144;         // 768*512
static constexpr size_t OFF_VR   = OFF_RT + 393216;          // 128*512

// ---------------------------------------------------------------------------
// K1: embedding accumulation + BN stat partials.
// Blocks 0..511: story, b = bid>>2, sentences [25*(bid&3), +25). Blocks 512..639: query.
__global__ __launch_bounds__(256) void k_embed(
    const int* __restrict__ story, const int* __restrict__ query,
    const float* __restrict__ we, const float* __restrict__ pos,
    float* __restrict__ semb, float* __restrict__ qemb, float* __restrict__ stats)
{
    int e = threadIdx.x;
    int bid = blockIdx.x;
    float pw[WW];
#pragma unroll
    for (int w = 0; w < WW; ++w) pw[w] = pos[w * EE + e];

    if (bid < 512) {
        int b = bid >> 2;
        int s0 = (bid & 3) * 25;
        float sum = 0.f, sq = 0.f;
        for (int s = s0; s < s0 + 25; ++s) {
            const int* idx = story + (b * SS + s) * WW;
            float acc = 0.f;
#pragma unroll
            for (int w = 0; w < WW; ++w) {
                int t = idx[w];
                acc = fmaf(we[(size_t)t * EE + e], pw[w], acc);
            }
            semb[(size_t)(b * SS + s) * EE + e] = acc;
            sum += acc;
            sq = fmaf(acc, acc, sq);
        }
        atomicAdd(&stats[0 * EE + e], sum);
        atomicAdd(&stats[1 * EE + e], sq);
    } else {
        int b = bid - 512;
        const int* idx = query + b * WW;
        float acc = 0.f;
#pragma unroll
        for (int w = 0; w < WW; ++w) {
            int t = idx[w];
            acc = fmaf(we[(size_t)t * EE + e], pw[w], acc);
        }
        qemb[b * EE + e] = acc;
        atomicAdd(&stats[2 * EE + e], acc);
        atomicAdd(&stats[3 * EE + e], acc * acc);
    }
}

// ---------------------------------------------------------------------------
// K2: finalize BN scale/shift; normalize query embedding in place
__global__ __launch_bounds__(256) void k_finalize(
    float* __restrict__ stats, float* __restrict__ qemb,
    const float* __restrict__ gs, const float* __restrict__ bs,
    const float* __restrict__ gq, const float* __restrict__ bq)
{
    int e = threadIdx.x;
    float ns = (float)(BB * SS);
    float mu = stats[0 * EE + e] / ns;
    float var = stats[1 * EE + e] / ns - mu * mu;
    float sc = rsqrtf(var + EPSB) * gs[e];
    stats[4 * EE + e] = sc;
    stats[5 * EE + e] = bs[e] - mu * sc;

    float nq = (float)BB;
    float muq = stats[2 * EE + e] / nq;
    float varq = stats[3 * EE + e] / nq - muq * muq;
    float scq = rsqrtf(varq + EPSB) * gq[e];
    float shq = bq[e] - muq * scq;
    for (int b = 0; b < BB; ++b) {
        qemb[b * EE + e] = fmaf(qemb[b * EE + e], scq, shq);
    }
}

// ---------------------------------------------------------------------------
// K3: LDS-tiled transposes (coalesced both sides; 32x33 pad kills bank conflicts).
// Blocks 0..255: w2t[k][j] = wW[j][512+k]   (512x512, 16x16 tiles of 32).
// Blocks 256..639: rt[k][j] = rW[j][k]      (768x512 out, 24 k-tiles x 16 j-tiles).
__global__ __launch_bounds__(256) void k_transpose(
    const float* __restrict__ wW, const float* __restrict__ rW,
    float* __restrict__ w2t, float* __restrict__ rt)
{
    __shared__ float tile[32][33];
    int tid = threadIdx.x;
    int c = tid & 31, r8 = tid >> 5;          // c: 0..31, r8: 0..7
    int b = blockIdx.x;
    if (b < 256) {
        int kt = b >> 4, jt = b & 15;         // k-tile, j-tile
        int j0 = jt * 32, k0 = kt * 32;
#pragma unroll
        for (int rr = 0; rr < 4; ++rr) {
            int r = r8 + rr * 8;
            tile[r][c] = wW[(size_t)(j0 + r) * 1024 + 512 + k0 + c];
        }
        __syncthreads();
#pragma unroll
        for (int rr = 0; rr < 4; ++rr) {
            int r = r8 + rr * 8;
            w2t[(size_t)(k0 + r) * 512 + j0 + c] = tile[c][r];
        }
    } else {
        int idx = b - 256;
        int kt = idx >> 4, jt = idx & 15;     // kt: 0..23, jt: 0..15
        int j0 = jt * 32, k0 = kt * 32;
#pragma unroll
        for (int rr = 0; rr < 4; ++rr) {
            int r = r8 + rr * 8;
            tile[r][c] = rW[(size_t)(j0 + r) * 768 + k0 + c];
        }
        __syncthreads();
#pragma unroll
        for (int rr = 0; rr < 4; ++rr) {
            int r = r8 + rr * 8;
            rt[(size_t)(k0 + r) * 512 + j0 + c] = tile[c][r];
        }
    }
}

// ---------------------------------------------------------------------------
// K4: k/v GEMM with fused BN on A-load and relu+bias epilogue.
// grid (200,8), block 256, tiles 64x64, K=256 in 4 chunks
__global__ __launch_bounds__(256) void k_kv(
    const float* __restrict__ semb, const float* __restrict__ stats,
    const float* __restrict__ Wk, const float* __restrict__ bk,
    const float* __restrict__ Wv, const float* __restrict__ bv,
    float* __restrict__ kout, float* __restrict__ vout)
{
    __shared__ float A[64][65];
    __shared__ float WK[64][65];
    __shared__ float WVs[64][65];
    int r0 = blockIdx.x * 64, c0 = blockIdx.y * 64;
    int tid = threadIdx.x;
    int tx = tid & 15, ty = tid >> 4;
    const float* scl = stats + 4 * EE;
    const float* shf = stats + 5 * EE;
    float ak[4][4] = {{0}}, av[4][4] = {{0}};
    for (int kc = 0; kc < 256; kc += 64) {
#pragma unroll
        for (int p = 0; p < 16; ++p) {
            int lin = p * 256 + tid;
            int row = lin >> 6, cc = lin & 63;
            A[row][cc]  = fmaf(semb[(size_t)(r0 + row) * EE + kc + cc], scl[kc + cc], shf[kc + cc]);
            WK[row][cc] = Wk[(size_t)(c0 + row) * EE + kc + cc];
            WVs[row][cc] = Wv[(size_t)(c0 + row) * EE + kc + cc];
        }
        __syncthreads();
        for (int kk = 0; kk < 64; ++kk) {
            float a[4], wk[4], wv[4];
#pragma unroll
            for (int q = 0; q < 4; ++q) {
                a[q] = A[ty * 4 + q][kk];
                wk[q] = WK[tx * 4 + q][kk];
                wv[q] = WVs[tx * 4 + q][kk];
            }
#pragma unroll
            for (int r = 0; r < 4; ++r)
#pragma unroll
                for (int c = 0; c < 4; ++c) {
                    ak[r][c] = fmaf(a[r], wk[c], ak[r][c]);
                    av[r][c] = fmaf(a[r], wv[c], av[r][c]);
                }
        }
        __syncthreads();
    }
#pragma unroll
    for (int r = 0; r < 4; ++r) {
        int row = r0 + ty * 4 + r;
#pragma unroll
        for (int c = 0; c < 4; ++c) {
            int col = c0 + tx * 4 + c;
            kout[(size_t)row * MM + col] = fmaxf(ak[r][c] + bk[col], 0.f);
            vout[(size_t)row * MM + col] = fmaxf(av[r][c] + bv[col], 0.f);
        }
    }
}

// ---------------------------------------------------------------------------
// K5: row LayerNorm in place over k buffer -> kn. grid 3200, block 256 (wave/row).
// Single fused (sum, sumsq) butterfly; var = E[x^2] - mean^2.
__global__ __launch_bounds__(256) void k_rowln(
    float* __restrict__ kbuf, const float* __restrict__ g, const float* __restrict__ bt)
{
    int row = blockIdx.x * 4 + (threadIdx.x >> 6);
    int lane = threadIdx.x & 63;
    float4* kr = (float4*)(kbuf + (size_t)row * MM);
    float4 x0 = kr[lane], x1 = kr[lane + 64];
    float s  = x0.x + x0.y + x0.z + x0.w + x1.x + x1.y + x1.z + x1.w;
    float s2 = x0.x * x0.x + x0.y * x0.y + x0.z * x0.z + x0.w * x0.w +
               x1.x * x1.x + x1.y * x1.y + x1.z * x1.z + x1.w * x1.w;
#pragma unroll
    for (int off = 32; off; off >>= 1) {
        s  += __shfl_down(s, off);
        s2 += __shfl_down(s2, off);
    }
    s = __shfl(s, 0);
    s2 = __shfl(s2, 0);
    float mean = s * (1.f / 512.f);
    float var = s2 * (1.f / 512.f) - mean * mean;
    float rstd = rsqrtf(var + EPSL);
    const float4* g4 = (const float4*)g;
    const float4* b4 = (const float4*)bt;
    float4 ga = g4[lane], gb = g4[lane + 64];
    float4 ba = b4[lane], bb = b4[lane + 64];
    float4 y0, y1;
    y0.x = fmaf((x0.x - mean) * rstd, ga.x, ba.x); y0.y = fmaf((x0.y - mean) * rstd, ga.y, ba.y);
    y0.z = fmaf((x0.z - mean) * rstd, ga.z, ba.z); y0.w = fmaf((x0.w - mean) * rstd, ga.w, ba.w);
    y1.x = fmaf((x1.x - mean) * rstd, gb.x, bb.x); y1.y = fmaf((x1.y - mean) * rstd, gb.y, bb.y);
    y1.z = fmaf((x1.z - mean) * rstd, gb.z, bb.z); y1.w = fmaf((x1.w - mean) * rstd, gb.w, bb.w);
    kr[lane] = y0;
    kr[lane + 64] = y1;
}

// ---------------------------------------------------------------------------
// K6: v2_pre = v @ W1^T + write_b. grid (200,8), block 256, K=512 in 8 chunks
__global__ __launch_bounds__(256) void k_v2p(
    const float* __restrict__ v, const float* __restrict__ wW,
    const float* __restrict__ wb, float* __restrict__ out)
{
    __shared__ float A[64][65];
    __shared__ float Wl[64][65];
    int r0 = blockIdx.x * 64, c0 = blockIdx.y * 64;
    int tid = threadIdx.x;
    int tx = tid & 15, ty = tid >> 4;
    float acc[4][4] = {{0}};
    for (int kc = 0; kc < 512; kc += 64) {
#pragma unroll
        for (int p = 0; p < 16; ++p) {
            int lin = p * 256 + tid;
            int row = lin >> 6, cc = lin & 63;
            A[row][cc] = v[(size_t)(r0 + row) * MM + kc + cc];
            Wl[row][cc] = wW[(size_t)(c0 + row) * 1024 + kc + cc];
        }
        __syncthreads();
        for (int kk = 0; kk < 64; ++kk) {
            float a[4], w[4];
#pragma unroll
            for (int q = 0; q < 4; ++q) {
                a[q] = A[ty * 4 + q][kk];
                w[q] = Wl[tx * 4 + q][kk];
            }
#pragma unroll
            for (int r = 0; r < 4; ++r)
#pragma unroll
                for (int c = 0; c < 4; ++c)
                    acc[r][c] = fmaf(a[r], w[c], acc[r][c]);
        }
        __syncthreads();
    }
#pragma unroll
    for (int r = 0; r < 4; ++r) {
        int row = r0 + ty * 4 + r;
#pragma unroll
        for (int c = 0; c < 4; ++c) {
            int col = c0 + tx * 4 + c;
            out[(size_t)row * MM + col] = acc[r][c] + wb[col];
        }
    }
}

// ---------------------------------------------------------------------------
// K7: the sequential Hebbian scan. One block per batch element, 1024 threads.
// Invariant at top of step t: vh[] = kn_t . m_t  (vh_0 = 0 since m_0 = 0).
// One fused m-pass per step: read m_t, write m_{t+1}, accumulate vh_{t+1}.
// m accesses are NON-TEMPORAL (keep w2t/kn/v2p resident in L2; m is
// L3-resident either way). g2/b2 hoisted to registers. Phase A matvec
// skipped at t=0 (vh == 0).
__global__ __launch_bounds__(1024) void k_scan(
    const float* __restrict__ kn_g,   // [B,S,512]
    const float* __restrict__ v2p,    // [B,S,512]  (vi@W1^T + write_b)
    const float* __restrict__ w2t,    // [512,512]  W2^T
    const float* __restrict__ g2, const float* __restrict__ b2,
    float* __restrict__ m)            // [B,512,512]
{
    __shared__ __align__(16) float kn[2][512];
    __shared__ __align__(16) float4 knpack[512];   // {c=GP*kn, d=1-GN*kn^2, kn_next, 0}
    __shared__ __align__(16) float vh[512];
    __shared__ __align__(16) float v2s[512];
    __shared__ __align__(16) float v2pre[512];
    __shared__ __align__(16) float part[8][512];
    __shared__ __align__(8) float2 red2[8];

    int b = blockIdx.x;
    int tid = threadIdx.x;
    int jq = tid & 127;
    int j4 = jq * 4;
    int ig = tid >> 7;                   // 0..7
    float* mb = m + (size_t)b * MM * MM;
    const float* knb = kn_g + (size_t)b * SS * MM;
    const float* v2pb = v2p + (size_t)b * SS * MM;

    float g2r = 0.f, b2r = 0.f;
    if (tid < 512) { g2r = g2[tid]; b2r = b2[tid]; }

    if (tid < 512) { kn[0][tid] = knb[tid]; vh[tid] = 0.f; }
    else           { v2pre[tid - 512] = v2pb[tid - 512]; }
    __syncthreads();

    for (int t = 0; t < SS; ++t) {
        int cur = t & 1, nxt = cur ^ 1;
        // ---- Phase A: part = W2^T . vh  (8 k-groups of 64); prefetch kn[t+1].
        //      t==0: vh == 0, skip the matvec and zero-fill part.
        {
            float4 acc = make_float4(0.f, 0.f, 0.f, 0.f);
            if (t > 0) {
                int k0 = ig * 64;
#pragma unroll 4
                for (int k = k0; k < k0 + 64; ++k) {
                    float vhk = vh[k];
                    float4 w = *(const float4*)(w2t + (size_t)k * 512 + j4);
                    acc.x = fmaf(vhk, w.x, acc.x);
                    acc.y = fmaf(vhk, w.y, acc.y);
                    acc.z = fmaf(vhk, w.z, acc.z);
                    acc.w = fmaf(vhk, w.w, acc.w);
                }
            }
            *(float4*)&part[ig][j4] = acc;
            if (tid < 512) kn[nxt][tid] = (t + 1 < SS) ? knb[(size_t)(t + 1) * MM + tid] : 0.f;
        }
        __syncthreads();
        // ---- Phase B: combine + fused single-pass LN -> v2s.
        //      threads>=512 build knpack {GP*kn_t, 1-GN*kn_t^2, kn_{t+1}};
        //      after the barrier they prefetch next v2pre (safe: all v2pre
        //      reads by tid<512 happen before the barrier).
        float pre = 0.f;
        if (tid < 512) {
#pragma unroll
            for (int q = 0; q < 8; ++q) pre += part[q][tid];
            pre += v2pre[tid];
        } else {
            int i = tid - 512;
            float kv = kn[cur][i];
            float kN = kn[nxt][i];
            knpack[i] = make_float4(GP * kv, 1.f - GN * kv * kv, kN, 0.f);
        }
        float s = (tid < 512) ? pre : 0.f;
        float s2 = s * s;
#pragma unroll
        for (int off = 32; off; off >>= 1) {
            s  += __shfl_down(s, off);
            s2 += __shfl_down(s2, off);
        }
        int wv = tid >> 6;
        if ((tid & 63) == 0 && wv < 8) red2[wv] = make_float2(s, s2);
        __syncthreads();
        if (tid < 512) {
            float ssum = 0.f, sqsum = 0.f;
#pragma unroll
            for (int q = 0; q < 8; ++q) { ssum += red2[q].x; sqsum += red2[q].y; }
            float mean = ssum * (1.f / 512.f);
            float var = sqsum * (1.f / 512.f) - mean * mean;
            float rstd = rsqrtf(var + EPSL);
            v2s[tid] = fmaf((pre - mean) * rstd, g2r, b2r);
        } else if (t + 1 < SS) {
            v2pre[tid - 512] = v2pb[(size_t)(t + 1) * MM + (tid - 512)];
        }
        __syncthreads();
        // ---- Phase C: fused m update + next-step matvec accumulation.
        //      knpack read is wave-uniform (one ds_read_b128 broadcast per i).
        //      m accessed non-temporally (bypass L2; it is L3-resident).
        {
            float4 w = *(const float4*)&v2s[j4];
            float4 vacc = make_float4(0.f, 0.f, 0.f, 0.f);
            if (t == 0) {
#pragma unroll 8
                for (int i = ig; i < 512; i += 8) {
                    float4 kp = knpack[i];
                    f32x4 mn;
                    mn.x = kp.x * w.x; mn.y = kp.x * w.y; mn.z = kp.x * w.z; mn.w = kp.x * w.w;
                    __builtin_nontemporal_store(mn, (f32x4*)(mb + (size_t)i * MM + j4));
                    vacc.x = fmaf(kp.z, mn.x, vacc.x);
                    vacc.y = fmaf(kp.z, mn.y, vacc.y);
                    vacc.z = fmaf(kp.z, mn.z, vacc.z);
                    vacc.w = fmaf(kp.z, mn.w, vacc.w);
                }
            } else {
#pragma unroll 8
                for (int i = ig; i < 512; i += 8) {
                    float4 kp = knpack[i];
                    f32x4 mo = __builtin_nontemporal_load((const f32x4*)(mb + (size_t)i * MM + j4));
                    f32x4 mn;
                    float cx = kp.x * w.x; mn.x = fmaf(mo.x, kp.y - cx, cx);
                    float cy = kp.x * w.y; mn.y = fmaf(mo.y, kp.y - cy, cy);
                    float cz = kp.x * w.z; mn.z = fmaf(mo.z, kp.y - cz, cz);
                    float cw = kp.x * w.w; mn.w = fmaf(mo.w, kp.y - cw, cw);
                    __builtin_nontemporal_store(mn, (f32x4*)(mb + (size_t)i * MM + j4));
                    vacc.x = fmaf(kp.z, mn.x, vacc.x);
                    vacc.y = fmaf(kp.z, mn.y, vacc.y);
                    vacc.z = fmaf(kp.z, mn.z, vacc.z);
                    vacc.w = fmaf(kp.z, mn.w, vacc.w);
                }
            }
            *(float4*)&part[ig][j4] = vacc;
        }
        __syncthreads();
        // ---- Phase D: reduce vh partials
        if (tid < 512) {
            float sj = 0.f;
#pragma unroll
            for (int q = 0; q < 8; ++q) sj += part[q][tid];
            vh[tid] = sj;
        }
        __syncthreads();
    }
}

// ---------------------------------------------------------------------------
// K8: 3 associative read hops. One block per b, 512 threads. m reads NT.
__global__ __launch_bounds__(512) void k_hops(
    const float* __restrict__ qn, const float* __restrict__ rt,
    const float* __restrict__ rb, const float* __restrict__ m,
    float* __restrict__ vr_out)
{
    __shared__ __align__(16) float q[256];
    __shared__ __align__(16) float vrs[512];
    __shared__ __align__(16) float kr[512];
    __shared__ __align__(16) float part[4][512];
    int b = blockIdx.x, tid = threadIdx.x;
    int jq = tid & 127, j4 = jq * 4, ig = tid >> 7;   // 0..3
    const float* mb = m + (size_t)b * MM * MM;
    if (tid < 256) q[tid] = qn[b * EE + tid];
    vrs[tid] = 0.f;
    __syncthreads();
    for (int hop = 0; hop < 3; ++hop) {
        float4 acc = make_float4(0.f, 0.f, 0.f, 0.f);
#pragma unroll 4
        for (int k = ig * 192; k < ig * 192 + 192; ++k) {
            float x = (k < 256) ? q[k] : vrs[k - 256];
            float4 w = *(const float4*)(rt + (size_t)k * 512 + j4);
            acc.x = fmaf(x, w.x, acc.x);
            acc.y = fmaf(x, w.y, acc.y);
            acc.z = fmaf(x, w.z, acc.z);
            acc.w = fmaf(x, w.w, acc.w);
        }
        *(float4*)&part[ig][j4] = acc;
        __syncthreads();
        {
            float s = rb[tid];
#pragma unroll
            for (int g = 0; g < 4; ++g) s += part[g][tid];
            kr[tid] = s;
        }
        __syncthreads();
        float4 vacc = make_float4(0.f, 0.f, 0.f, 0.f);
#pragma unroll 8
        for (int i = ig; i < 512; i += 4) {
            float ki = kr[i];
            f32x4 mv = __builtin_nontemporal_load((const f32x4*)(mb + (size_t)i * MM + j4));
            vacc.x = fmaf(ki, mv.x, vacc.x);
            vacc.y = fmaf(ki, mv.y, vacc.y);
            vacc.z = fmaf(ki, mv.z, vacc.z);
            vacc.w = fmaf(ki, mv.w, vacc.w);
        }
        *(float4*)&part[ig][j4] = vacc;
        __syncthreads();
        {
            float s = 0.f;
#pragma unroll
            for (int g = 0; g < 4; ++g) s += part[g][tid];
            vrs[tid] = s;
        }
        __syncthreads();
    }
    vr_out[(size_t)b * MM + tid] = vrs[tid];
}

// ---------------------------------------------------------------------------
// K9: logits = vr @ out_W^T + out_b. grid (40 vtiles, 8 btiles), block 256.
// W-chunk held in registers; vs reads are same-address LDS broadcasts (free).
__global__ __launch_bounds__(256) void k_out(
    const float* __restrict__ vr, const float* __restrict__ oW,
    const float* __restrict__ ob, float* __restrict__ out)
{
    __shared__ __align__(16) float vs[16][512];
    int v0 = blockIdx.x * 256, b0 = blockIdx.y * 16;
    int tid = threadIdx.x;
    {
        const float4* src = (const float4*)(vr + (size_t)b0 * 512);
        float4* dst = (float4*)&vs[0][0];
#pragma unroll
        for (int p = 0; p < 8; ++p) dst[p * 256 + tid] = src[p * 256 + tid];
    }
    float acc[16];
#pragma unroll
    for (int i = 0; i < 16; ++i) acc[i] = 0.f;
    int v = v0 + tid;
    bool valid = v < VV;
    float bias = valid ? ob[v] : 0.f;
    __syncthreads();
    for (int kc = 0; kc < 512; kc += 16) {
        float4 tmp[4];
        const float4* src = (const float4*)(oW + (size_t)(valid ? v : 0) * 512 + kc);
#pragma unroll
        for (int p = 0; p < 4; ++p) tmp[p] = src[p];
#pragma unroll
        for (int p = 0; p < 4; ++p) {
            float w0 = tmp[p].x, w1 = tmp[p].y, w2 = tmp[p].z, w3 = tmp[p].w;
            int c0 = kc + p * 4;
#pragma unroll
            for (int bb = 0; bb < 16; ++bb) {
                float4 vv = *(const float4*)&vs[bb][c0];
                acc[bb] = fmaf(w0, vv.x, fmaf(w1, vv.y, fmaf(w2, vv.z, fmaf(w3, vv.w, acc[bb]))));
            }
        }
    }
    if (valid) {
#pragma unroll
        for (int bb = 0; bb < 16; ++bb)
            out[(size_t)(b0 + bb) * VV + v] = acc[bb] + bias;
    }
}

// ---------------------------------------------------------------------------
extern "C" void kernel_launch(void* const* d_in, const int* in_sizes, int n_in,
                              void* d_out, int out_size, void* d_ws, size_t ws_size,
                              hipStream_t stream)
{
    const int*   story = (const int*)d_in[0];
    const int*   query = (const int*)d_in[1];
    const float* we    = (const float*)d_in[2];
    const float* pos   = (const float*)d_in[3];
    const float* bsg   = (const float*)d_in[4];
    const float* bsb   = (const float*)d_in[5];
    const float* bqg   = (const float*)d_in[6];
    const float* bqb   = (const float*)d_in[7];
    const float* Wk    = (const float*)d_in[8];
    const float* bk    = (const float*)d_in[9];
    const float* Wv    = (const float*)d_in[10];
    const float* bv    = (const float*)d_in[11];
    const float* wW    = (const float*)d_in[12];
    const float* wb    = (const float*)d_in[13];
    const float* g1    = (const float*)d_in[14];
    const float* b1    = (const float*)d_in[15];
    const float* g2    = (const float*)d_in[16];
    const float* b2    = (const float*)d_in[17];
    const float* rW    = (const float*)d_in[18];
    const float* rb    = (const float*)d_in[19];
    const float* oW    = (const float*)d_in[20];
    const float* ob    = (const float*)d_in[21];

    float* ws   = (float*)d_ws;
    float* mbuf = ws + OFF_M;
    float* semb = ws + OFF_SEMB;   // aliases mbuf head (dead before k_scan)
    float* vbuf = ws + OFF_V;      // aliases mbuf (dead before k_scan)
    float* qemb = ws + OFF_QEMB;
    float* stat = ws + OFF_STAT;
    float* kbuf = ws + OFF_K;      // becomes kn after k_rowln
    float* v2p  = ws + OFF_V2P;
    float* w2t  = ws + OFF_W2T;
    float* rt   = ws + OFF_RT;
    float* vr   = ws + OFF_VR;

    hipMemsetAsync(stat, 0, 4 * EE * sizeof(float), stream);
    k_embed<<<640, 256, 0, stream>>>(story, query, we, pos, semb, qemb, stat);
    k_finalize<<<1, 256, 0, stream>>>(stat, qemb, bsg, bsb, bqg, bqb);
    k_transpose<<<640, 256, 0, stream>>>(wW, rW, w2t, rt);
    k_kv<<<dim3(200, 8), 256, 0, stream>>>(semb, stat, Wk, bk, Wv, bv, kbuf, vbuf);
    k_rowln<<<3200, 256, 0, stream>>>(kbuf, g1, b1);
    k_v2p<<<dim3(200, 8), 256, 0, stream>>>(vbuf, wW, wb, v2p);
    k_scan<<<128, 1024, 0, stream>>>(kbuf, v2p, w2t, g2, b2, mbuf);
    k_hops<<<128, 512, 0, stream>>>(qemb, rt, rb, mbuf, vr);
    k_out<<<dim3(40, 8), 256, 0, stream>>>(vr, oW, ob, (float*)d_out);
}

// Round 11
// 5164.120 us; speedup vs baseline: 1.2163x; 1.2163x over previous
//
#include <hip/hip_runtime.h>
#include <hip/hip_bf16.h>

// Problem constants
#define BB   128
#define SS   100
#define WW   12
#define EE   256
#define MM   512
#define VV   10000
#define GP   0.1f
#define GN   0.1f
#define EPSB 1e-5f
#define EPSL 1e-5f

typedef float f32x4 __attribute__((ext_vector_type(4)));

// Workspace layout (floats), total 47417344 floats = 190 MB.
// m occupies [0, 33554432); semb and vbuf ALIAS its head — they are dead
// before k_scan writes m (stream-ordered), which also keeps ws small.
// r10 post-mortem: NONTEMPORAL m hints pushed all m traffic to HBM
// (WRITE_SIZE 13.1 GB = 100 x 128 MiB exactly) — nt defeats Infinity-Cache
// residency on gfx950. m must use PLAIN loads/stores so it stays in L3.
static constexpr size_t OFF_M    = 0;                        // 128*512*512
static constexpr size_t OFF_SEMB = 0;                        // 12800*256 (alias, dead pre-scan)
static constexpr size_t OFF_V    = 3276800;                  // 12800*512 (alias, dead pre-scan)
static constexpr size_t OFF_QEMB = 33554432;                 // 128*256
static constexpr size_t OFF_STAT = OFF_QEMB + 32768;         // 8*256
static constexpr size_t OFF_K    = OFF_STAT + 2048;          // 12800*512 (becomes kn in-place)
static constexpr size_t OFF_V2P  = OFF_K + 6553600;          // 12800*512
static constexpr size_t OFF_W2T  = OFF_V2P + 6553600;        // 512*512
static constexpr size_t OFF_RT   = OFF_W2T + 262144;         // 768*512
static constexpr size_t OFF_VR   = OFF_RT + 393216;          // 128*512

// ---------------------------------------------------------------------------
// K1: embedding accumulation + BN stat partials.
// Blocks 0..511: story, b = bid>>2, sentences [25*(bid&3), +25). Blocks 512..639: query.
__global__ __launch_bounds__(256) void k_embed(
    const int* __restrict__ story, const int* __restrict__ query,
    const float* __restrict__ we, const float* __restrict__ pos,
    float* __restrict__ semb, float* __restrict__ qemb, float* __restrict__ stats)
{
    int e = threadIdx.x;
    int bid = blockIdx.x;
    float pw[WW];
#pragma unroll
    for (int w = 0; w < WW; ++w) pw[w] = pos[w * EE + e];

    if (bid < 512) {
        int b = bid >> 2;
        int s0 = (bid & 3) * 25;
        float sum = 0.f, sq = 0.f;
        for (int s = s0; s < s0 + 25; ++s) {
            const int* idx = story + (b * SS + s) * WW;
            float acc = 0.f;
#pragma unroll
            for (int w = 0; w < WW; ++w) {
                int t = idx[w];
                acc = fmaf(we[(size_t)t * EE + e], pw[w], acc);
            }
            semb[(size_t)(b * SS + s) * EE + e] = acc;
            sum += acc;
            sq = fmaf(acc, acc, sq);
        }
        atomicAdd(&stats[0 * EE + e], sum);
        atomicAdd(&stats[1 * EE + e], sq);
    } else {
        int b = bid - 512;
        const int* idx = query + b * WW;
        float acc = 0.f;
#pragma unroll
        for (int w = 0; w < WW; ++w) {
            int t = idx[w];
            acc = fmaf(we[(size_t)t * EE + e], pw[w], acc);
        }
        qemb[b * EE + e] = acc;
        atomicAdd(&stats[2 * EE + e], acc);
        atomicAdd(&stats[3 * EE + e], acc * acc);
    }
}

// ---------------------------------------------------------------------------
// K2: finalize BN scale/shift; normalize query embedding in place
__global__ __launch_bounds__(256) void k_finalize(
    float* __restrict__ stats, float* __restrict__ qemb,
    const float* __restrict__ gs, const float* __restrict__ bs,
    const float* __restrict__ gq, const float* __restrict__ bq)
{
    int e = threadIdx.x;
    float ns = (float)(BB * SS);
    float mu = stats[0 * EE + e] / ns;
    float var = stats[1 * EE + e] / ns - mu * mu;
    float sc = rsqrtf(var + EPSB) * gs[e];
    stats[4 * EE + e] = sc;
    stats[5 * EE + e] = bs[e] - mu * sc;

    float nq = (float)BB;
    float muq = stats[2 * EE + e] / nq;
    float varq = stats[3 * EE + e] / nq - muq * muq;
    float scq = rsqrtf(varq + EPSB) * gq[e];
    float shq = bq[e] - muq * scq;
    for (int b = 0; b < BB; ++b) {
        qemb[b * EE + e] = fmaf(qemb[b * EE + e], scq, shq);
    }
}

// ---------------------------------------------------------------------------
// K3: LDS-tiled transposes (coalesced both sides; 32x33 pad kills bank conflicts).
// Blocks 0..255: w2t[k][j] = wW[j][512+k]   (512x512, 16x16 tiles of 32).
// Blocks 256..639: rt[k][j] = rW[j][k]      (768x512 out, 24 k-tiles x 16 j-tiles).
__global__ __launch_bounds__(256) void k_transpose(
    const float* __restrict__ wW, const float* __restrict__ rW,
    float* __restrict__ w2t, float* __restrict__ rt)
{
    __shared__ float tile[32][33];
    int tid = threadIdx.x;
    int c = tid & 31, r8 = tid >> 5;          // c: 0..31, r8: 0..7
    int b = blockIdx.x;
    if (b < 256) {
        int kt = b >> 4, jt = b & 15;         // k-tile, j-tile
        int j0 = jt * 32, k0 = kt * 32;
#pragma unroll
        for (int rr = 0; rr < 4; ++rr) {
            int r = r8 + rr * 8;
            tile[r][c] = wW[(size_t)(j0 + r) * 1024 + 512 + k0 + c];
        }
        __syncthreads();
#pragma unroll
        for (int rr = 0; rr < 4; ++rr) {
            int r = r8 + rr * 8;
            w2t[(size_t)(k0 + r) * 512 + j0 + c] = tile[c][r];
        }
    } else {
        int idx = b - 256;
        int kt = idx >> 4, jt = idx & 15;     // kt: 0..23, jt: 0..15
        int j0 = jt * 32, k0 = kt * 32;
#pragma unroll
        for (int rr = 0; rr < 4; ++rr) {
            int r = r8 + rr * 8;
            tile[r][c] = rW[(size_t)(j0 + r) * 768 + k0 + c];
        }
        __syncthreads();
#pragma unroll
        for (int rr = 0; rr < 4; ++rr) {
            int r = r8 + rr * 8;
            rt[(size_t)(k0 + r) * 512 + j0 + c] = tile[c][r];
        }
    }
}

// ---------------------------------------------------------------------------
// K4: k/v GEMM with fused BN on A-load and relu+bias epilogue.
// grid (200,8), block 256, tiles 64x64, K=256 in 4 chunks
__global__ __launch_bounds__(256) void k_kv(
    const float* __restrict__ semb, const float* __restrict__ stats,
    const float* __restrict__ Wk, const float* __restrict__ bk,
    const float* __restrict__ Wv, const float* __restrict__ bv,
    float* __restrict__ kout, float* __restrict__ vout)
{
    __shared__ float A[64][65];
    __shared__ float WK[64][65];
    __shared__ float WVs[64][65];
    int r0 = blockIdx.x * 64, c0 = blockIdx.y * 64;
    int tid = threadIdx.x;
    int tx = tid & 15, ty = tid >> 4;
    const float* scl = stats + 4 * EE;
    const float* shf = stats + 5 * EE;
    float ak[4][4] = {{0}}, av[4][4] = {{0}};
    for (int kc = 0; kc < 256; kc += 64) {
#pragma unroll
        for (int p = 0; p < 16; ++p) {
            int lin = p * 256 + tid;
            int row = lin >> 6, cc = lin & 63;
            A[row][cc]  = fmaf(semb[(size_t)(r0 + row) * EE + kc + cc], scl[kc + cc], shf[kc + cc]);
            WK[row][cc] = Wk[(size_t)(c0 + row) * EE + kc + cc];
            WVs[row][cc] = Wv[(size_t)(c0 + row) * EE + kc + cc];
        }
        __syncthreads();
        for (int kk = 0; kk < 64; ++kk) {
            float a[4], wk[4], wv[4];
#pragma unroll
            for (int q = 0; q < 4; ++q) {
                a[q] = A[ty * 4 + q][kk];
                wk[q] = WK[tx * 4 + q][kk];
                wv[q] = WVs[tx * 4 + q][kk];
            }
#pragma unroll
            for (int r = 0; r < 4; ++r)
#pragma unroll
                for (int c = 0; c < 4; ++c) {
                    ak[r][c] = fmaf(a[r], wk[c], ak[r][c]);
                    av[r][c] = fmaf(a[r], wv[c], av[r][c]);
                }
        }
        __syncthreads();
    }
#pragma unroll
    for (int r = 0; r < 4; ++r) {
        int row = r0 + ty * 4 + r;
#pragma unroll
        for (int c = 0; c < 4; ++c) {
            int col = c0 + tx * 4 + c;
            kout[(size_t)row * MM + col] = fmaxf(ak[r][c] + bk[col], 0.f);
            vout[(size_t)row * MM + col] = fmaxf(av[r][c] + bv[col], 0.f);
        }
    }
}

// ---------------------------------------------------------------------------
// K5: row LayerNorm in place over k buffer -> kn. grid 3200, block 256 (wave/row).
// Single fused (sum, sumsq) butterfly; var = E[x^2] - mean^2.
__global__ __launch_bounds__(256) void k_rowln(
    float* __restrict__ kbuf, const float* __restrict__ g, const float* __restrict__ bt)
{
    int row = blockIdx.x * 4 + (threadIdx.x >> 6);
    int lane = threadIdx.x & 63;
    float4* kr = (float4*)(kbuf + (size_t)row * MM);
    float4 x0 = kr[lane], x1 = kr[lane + 64];
    float s  = x0.x + x0.y + x0.z + x0.w + x1.x + x1.y + x1.z + x1.w;
    float s2 = x0.x * x0.x + x0.y * x0.y + x0.z * x0.z + x0.w * x0.w +
               x1.x * x1.x + x1.y * x1.y + x1.z * x1.z + x1.w * x1.w;
#pragma unroll
    for (int off = 32; off; off >>= 1) {
        s  += __shfl_down(s, off);
        s2 += __shfl_down(s2, off);
    }
    s = __shfl(s, 0);
    s2 = __shfl(s2, 0);
    float mean = s * (1.f / 512.f);
    float var = s2 * (1.f / 512.f) - mean * mean;
    float rstd = rsqrtf(var + EPSL);
    const float4* g4 = (const float4*)g;
    const float4* b4 = (const float4*)bt;
    float4 ga = g4[lane], gb = g4[lane + 64];
    float4 ba = b4[lane], bb = b4[lane + 64];
    float4 y0, y1;
    y0.x = fmaf((x0.x - mean) * rstd, ga.x, ba.x); y0.y = fmaf((x0.y - mean) * rstd, ga.y, ba.y);
    y0.z = fmaf((x0.z - mean) * rstd, ga.z, ba.z); y0.w = fmaf((x0.w - mean) * rstd, ga.w, ba.w);
    y1.x = fmaf((x1.x - mean) * rstd, gb.x, bb.x); y1.y = fmaf((x1.y - mean) * rstd, gb.y, bb.y);
    y1.z = fmaf((x1.z - mean) * rstd, gb.z, bb.z); y1.w = fmaf((x1.w - mean) * rstd, gb.w, bb.w);
    kr[lane] = y0;
    kr[lane + 64] = y1;
}

// ---------------------------------------------------------------------------
// K6: v2_pre = v @ W1^T + write_b. grid (200,8), block 256, K=512 in 8 chunks
__global__ __launch_bounds__(256) void k_v2p(
    const float* __restrict__ v, const float* __restrict__ wW,
    const float* __restrict__ wb, float* __restrict__ out)
{
    __shared__ float A[64][65];
    __shared__ float Wl[64][65];
    int r0 = blockIdx.x * 64, c0 = blockIdx.y * 64;
    int tid = threadIdx.x;
    int tx = tid & 15, ty = tid >> 4;
    float acc[4][4] = {{0}};
    for (int kc = 0; kc < 512; kc += 64) {
#pragma unroll
        for (int p = 0; p < 16; ++p) {
            int lin = p * 256 + tid;
            int row = lin >> 6, cc = lin & 63;
            A[row][cc] = v[(size_t)(r0 + row) * MM + kc + cc];
            Wl[row][cc] = wW[(size_t)(c0 + row) * 1024 + kc + cc];
        }
        __syncthreads();
        for (int kk = 0; kk < 64; ++kk) {
            float a[4], w[4];
#pragma unroll
            for (int q = 0; q < 4; ++q) {
                a[q] = A[ty * 4 + q][kk];
                w[q] = Wl[tx * 4 + q][kk];
            }
#pragma unroll
            for (int r = 0; r < 4; ++r)
#pragma unroll
                for (int c = 0; c < 4; ++c)
                    acc[r][c] = fmaf(a[r], w[c], acc[r][c]);
        }
        __syncthreads();
    }
#pragma unroll
    for (int r = 0; r < 4; ++r) {
        int row = r0 + ty * 4 + r;
#pragma unroll
        for (int c = 0; c < 4; ++c) {
            int col = c0 + tx * 4 + c;
            out[(size_t)row * MM + col] = acc[r][c] + wb[col];
        }
    }
}

// ---------------------------------------------------------------------------
// K7: the sequential Hebbian scan. One block per batch element, 1024 threads.
// Invariant at top of step t: vh[] = kn_t . m_t  (vh_0 = 0 since m_0 = 0).
// One fused m-pass per step: read m_t, write m_{t+1}, accumulate vh_{t+1}.
// m uses PLAIN loads/stores (L3-resident; r10 showed nt => all-HBM).
// g2/b2 hoisted to registers. Phase A matvec skipped at t=0 (vh == 0).
__global__ __launch_bounds__(1024) void k_scan(
    const float* __restrict__ kn_g,   // [B,S,512]
    const float* __restrict__ v2p,    // [B,S,512]  (vi@W1^T + write_b)
    const float* __restrict__ w2t,    // [512,512]  W2^T
    const float* __restrict__ g2, const float* __restrict__ b2,
    float* __restrict__ m)            // [B,512,512]
{
    __shared__ __align__(16) float kn[2][512];
    __shared__ __align__(16) float4 knpack[512];   // {c=GP*kn, d=1-GN*kn^2, kn_next, 0}
    __shared__ __align__(16) float vh[512];
    __shared__ __align__(16) float v2s[512];
    __shared__ __align__(16) float v2pre[512];
    __shared__ __align__(16) float part[8][512];
    __shared__ __align__(8) float2 red2[8];

    int b = blockIdx.x;
    int tid = threadIdx.x;
    int jq = tid & 127;
    int j4 = jq * 4;
    int ig = tid >> 7;                   // 0..7
    float* mb = m + (size_t)b * MM * MM;
    const float* knb = kn_g + (size_t)b * SS * MM;
    const float* v2pb = v2p + (size_t)b * SS * MM;

    float g2r = 0.f, b2r = 0.f;
    if (tid < 512) { g2r = g2[tid]; b2r = b2[tid]; }

    if (tid < 512) { kn[0][tid] = knb[tid]; vh[tid] = 0.f; }
    else           { v2pre[tid - 512] = v2pb[tid - 512]; }
    __syncthreads();

    for (int t = 0; t < SS; ++t) {
        int cur = t & 1, nxt = cur ^ 1;
        // ---- Phase A: part = W2^T . vh  (8 k-groups of 64); prefetch kn[t+1].
        //      t==0: vh == 0, skip the matvec and zero-fill part.
        {
            float4 acc = make_float4(0.f, 0.f, 0.f, 0.f);
            if (t > 0) {
                int k0 = ig * 64;
#pragma unroll 4
                for (int k = k0; k < k0 + 64; ++k) {
                    float vhk = vh[k];
                    float4 w = *(const float4*)(w2t + (size_t)k * 512 + j4);
                    acc.x = fmaf(vhk, w.x, acc.x);
                    acc.y = fmaf(vhk, w.y, acc.y);
                    acc.z = fmaf(vhk, w.z, acc.z);
                    acc.w = fmaf(vhk, w.w, acc.w);
                }
            }
            *(float4*)&part[ig][j4] = acc;
            if (tid < 512) kn[nxt][tid] = (t + 1 < SS) ? knb[(size_t)(t + 1) * MM + tid] : 0.f;
        }
        __syncthreads();
        // ---- Phase B: combine + fused single-pass LN -> v2s.
        //      threads>=512 build knpack {GP*kn_t, 1-GN*kn_t^2, kn_{t+1}};
        //      after the barrier they prefetch next v2pre (safe: all v2pre
        //      reads by tid<512 happen before the barrier).
        float pre = 0.f;
        if (tid < 512) {
#pragma unroll
            for (int q = 0; q < 8; ++q) pre += part[q][tid];
            pre += v2pre[tid];
        } else {
            int i = tid - 512;
            float kv = kn[cur][i];
            float kN = kn[nxt][i];
            knpack[i] = make_float4(GP * kv, 1.f - GN * kv * kv, kN, 0.f);
        }
        float s = (tid < 512) ? pre : 0.f;
        float s2 = s * s;
#pragma unroll
        for (int off = 32; off; off >>= 1) {
            s  += __shfl_down(s, off);
            s2 += __shfl_down(s2, off);
        }
        int wv = tid >> 6;
        if ((tid & 63) == 0 && wv < 8) red2[wv] = make_float2(s, s2);
        __syncthreads();
        if (tid < 512) {
            float ssum = 0.f, sqsum = 0.f;
#pragma unroll
            for (int q = 0; q < 8; ++q) { ssum += red2[q].x; sqsum += red2[q].y; }
            float mean = ssum * (1.f / 512.f);
            float var = sqsum * (1.f / 512.f) - mean * mean;
            float rstd = rsqrtf(var + EPSL);
            v2s[tid] = fmaf((pre - mean) * rstd, g2r, b2r);
        } else if (t + 1 < SS) {
            v2pre[tid - 512] = v2pb[(size_t)(t + 1) * MM + (tid - 512)];
        }
        __syncthreads();
        // ---- Phase C: fused m update + next-step matvec accumulation.
        //      knpack read is wave-uniform (one ds_read_b128 broadcast per i).
        //      m via plain cached accesses — stays Infinity-Cache-resident.
        {
            float4 w = *(const float4*)&v2s[j4];
            float4 vacc = make_float4(0.f, 0.f, 0.f, 0.f);
            if (t == 0) {
#pragma unroll 8
                for (int i = ig; i < 512; i += 8) {
                    float4 kp = knpack[i];
                    float4 mn;
                    mn.x = kp.x * w.x; mn.y = kp.x * w.y; mn.z = kp.x * w.z; mn.w = kp.x * w.w;
                    *(float4*)(mb + (size_t)i * MM + j4) = mn;
                    vacc.x = fmaf(kp.z, mn.x, vacc.x);
                    vacc.y = fmaf(kp.z, mn.y, vacc.y);
                    vacc.z = fmaf(kp.z, mn.z, vacc.z);
                    vacc.w = fmaf(kp.z, mn.w, vacc.w);
                }
            } else {
#pragma unroll 8
                for (int i = ig; i < 512; i += 8) {
                    float4 kp = knpack[i];
                    float4* mp = (float4*)(mb + (size_t)i * MM + j4);
                    float4 mo = *mp;
                    float4 mn;
                    float cx = kp.x * w.x; mn.x = fmaf(mo.x, kp.y - cx, cx);
                    float cy = kp.x * w.y; mn.y = fmaf(mo.y, kp.y - cy, cy);
                    float cz = kp.x * w.z; mn.z = fmaf(mo.z, kp.y - cz, cz);
                    float cw = kp.x * w.w; mn.w = fmaf(mo.w, kp.y - cw, cw);
                    *mp = mn;
                    vacc.x = fmaf(kp.z, mn.x, vacc.x);
                    vacc.y = fmaf(kp.z, mn.y, vacc.y);
                    vacc.z = fmaf(kp.z, mn.z, vacc.z);
                    vacc.w = fmaf(kp.z, mn.w, vacc.w);
                }
            }
            *(float4*)&part[ig][j4] = vacc;
        }
        __syncthreads();
        // ---- Phase D: reduce vh partials
        if (tid < 512) {
            float sj = 0.f;
#pragma unroll
            for (int q = 0; q < 8; ++q) sj += part[q][tid];
            vh[tid] = sj;
        }
        __syncthreads();
    }
}

// ---------------------------------------------------------------------------
// K8: 3 associative read hops. One block per b, 512 threads. Plain m reads.
__global__ __launch_bounds__(512) void k_hops(
    const float* __restrict__ qn, const float* __restrict__ rt,
    const float* __restrict__ rb, const float* __restrict__ m,
    float* __restrict__ vr_out)
{
    __shared__ __align__(16) float q[256];
    __shared__ __align__(16) float vrs[512];
    __shared__ __align__(16) float kr[512];
    __shared__ __align__(16) float part[4][512];
    int b = blockIdx.x, tid = threadIdx.x;
    int jq = tid & 127, j4 = jq * 4, ig = tid >> 7;   // 0..3
    const float* mb = m + (size_t)b * MM * MM;
    if (tid < 256) q[tid] = qn[b * EE + tid];
    vrs[tid] = 0.f;
    __syncthreads();
    for (int hop = 0; hop < 3; ++hop) {
        float4 acc = make_float4(0.f, 0.f, 0.f, 0.f);
#pragma unroll 4
        for (int k = ig * 192; k < ig * 192 + 192; ++k) {
            float x = (k < 256) ? q[k] : vrs[k - 256];
            float4 w = *(const float4*)(rt + (size_t)k * 512 + j4);
            acc.x = fmaf(x, w.x, acc.x);
            acc.y = fmaf(x, w.y, acc.y);
            acc.z = fmaf(x, w.z, acc.z);
            acc.w = fmaf(x, w.w, acc.w);
        }
        *(float4*)&part[ig][j4] = acc;
        __syncthreads();
        {
            float s = rb[tid];
#pragma unroll
            for (int g = 0; g < 4; ++g) s += part[g][tid];
            kr[tid] = s;
        }
        __syncthreads();
        float4 vacc = make_float4(0.f, 0.f, 0.f, 0.f);
#pragma unroll 8
        for (int i = ig; i < 512; i += 4) {
            float ki = kr[i];
            float4 mv = *(const float4*)(mb + (size_t)i * MM + j4);
            vacc.x = fmaf(ki, mv.x, vacc.x);
            vacc.y = fmaf(ki, mv.y, vacc.y);
            vacc.z = fmaf(ki, mv.z, vacc.z);
            vacc.w = fmaf(ki, mv.w, vacc.w);
        }
        *(float4*)&part[ig][j4] = vacc;
        __syncthreads();
        {
            float s = 0.f;
#pragma unroll
            for (int g = 0; g < 4; ++g) s += part[g][tid];
            vrs[tid] = s;
        }
        __syncthreads();
    }
    vr_out[(size_t)b * MM + tid] = vrs[tid];
}

// ---------------------------------------------------------------------------
// K9: logits = vr @ out_W^T + out_b. grid (40 vtiles, 8 btiles), block 256.
// W-chunk held in registers; vs reads are same-address LDS broadcasts (free).
__global__ __launch_bounds__(256) void k_out(
    const float* __restrict__ vr, const float* __restrict__ oW,
    const float* __restrict__ ob, float* __restrict__ out)
{
    __shared__ __align__(16) float vs[16][512];
    int v0 = blockIdx.x * 256, b0 = blockIdx.y * 16;
    int tid = threadIdx.x;
    {
        const float4* src = (const float4*)(vr + (size_t)b0 * 512);
        float4* dst = (float4*)&vs[0][0];
#pragma unroll
        for (int p = 0; p < 8; ++p) dst[p * 256 + tid] = src[p * 256 + tid];
    }
    float acc[16];
#pragma unroll
    for (int i = 0; i < 16; ++i) acc[i] = 0.f;
    int v = v0 + tid;
    bool valid = v < VV;
    float bias = valid ? ob[v] : 0.f;
    __syncthreads();
    for (int kc = 0; kc < 512; kc += 16) {
        float4 tmp[4];
        const float4* src = (const float4*)(oW + (size_t)(valid ? v : 0) * 512 + kc);
#pragma unroll
        for (int p = 0; p < 4; ++p) tmp[p] = src[p];
#pragma unroll
        for (int p = 0; p < 4; ++p) {
            float w0 = tmp[p].x, w1 = tmp[p].y, w2 = tmp[p].z, w3 = tmp[p].w;
            int c0 = kc + p * 4;
#pragma unroll
            for (int bb = 0; bb < 16; ++bb) {
                float4 vv = *(const float4*)&vs[bb][c0];
                acc[bb] = fmaf(w0, vv.x, fmaf(w1, vv.y, fmaf(w2, vv.z, fmaf(w3, vv.w, acc[bb]))));
            }
        }
    }
    if (valid) {
#pragma unroll
        for (int bb = 0; bb < 16; ++bb)
            out[(size_t)(b0 + bb) * VV + v] = acc[bb] + bias;
    }
}

// ---------------------------------------------------------------------------
extern "C" void kernel_launch(void* const* d_in, const int* in_sizes, int n_in,
                              void* d_out, int out_size, void* d_ws, size_t ws_size,
                              hipStream_t stream)
{
    const int*   story = (const int*)d_in[0];
    const int*   query = (const int*)d_in[1];
    const float* we    = (const float*)d_in[2];
    const float* pos   = (const float*)d_in[3];
    const float* bsg   = (const float*)d_in[4];
    const float* bsb   = (const float*)d_in[5];
    const float* bqg   = (const float*)d_in[6];
    const float* bqb   = (const float*)d_in[7];
    const float* Wk    = (const float*)d_in[8];
    const float* bk    = (const float*)d_in[9];
    const float* Wv    = (const float*)d_in[10];
    const float* bv    = (const float*)d_in[11];
    const float* wW    = (const float*)d_in[12];
    const float* wb    = (const float*)d_in[13];
    const float* g1    = (const float*)d_in[14];
    const float* b1    = (const float*)d_in[15];
    const float* g2    = (const float*)d_in[16];
    const float* b2    = (const float*)d_in[17];
    const float* rW    = (const float*)d_in[18];
    const float* rb    = (const float*)d_in[19];
    const float* oW    = (const float*)d_in[20];
    const float* ob    = (const float*)d_in[21];

    float* ws   = (float*)d_ws;
    float* mbuf = ws + OFF_M;
    float* semb = ws + OFF_SEMB;   // aliases mbuf head (dead before k_scan)
    float* vbuf = ws + OFF_V;      // aliases mbuf (dead before k_scan)
    float* qemb = ws + OFF_QEMB;
    float* stat = ws + OFF_STAT;
    float* kbuf = ws + OFF_K;      // becomes kn after k_rowln
    float* v2p  = ws + OFF_V2P;
    float* w2t  = ws + OFF_W2T;
    float* rt   = ws + OFF_RT;
    float* vr   = ws + OFF_VR;

    hipMemsetAsync(stat, 0, 4 * EE * sizeof(float), stream);
    k_embed<<<640, 256, 0, stream>>>(story, query, we, pos, semb, qemb, stat);
    k_finalize<<<1, 256, 0, stream>>>(stat, qemb, bsg, bsb, bqg, bqb);
    k_transpose<<<640, 256, 0, stream>>>(wW, rW, w2t, rt);
    k_kv<<<dim3(200, 8), 256, 0, stream>>>(semb, stat, Wk, bk, Wv, bv, kbuf, vbuf);
    k_rowln<<<3200, 256, 0, stream>>>(kbuf, g1, b1);
    k_v2p<<<dim3(200, 8), 256, 0, stream>>>(vbuf, wW, wb, v2p);
    k_scan<<<128, 1024, 0, stream>>>(kbuf, v2p, w2t, g2, b2, mbuf);
    k_hops<<<128, 512, 0, stream>>>(qemb, rt, rb, mbuf, vr);
    k_out<<<dim3(40, 8), 256, 0, stream>>>(vr, oW, ob, (float*)d_out);
}

// Round 13
// 3047.262 us; speedup vs baseline: 2.0613x; 1.6947x over previous
//
#include <hip/hip_runtime.h>
#include <hip/hip_bf16.h>

// Problem constants
#define BB   128
#define SS   100
#define WW   12
#define EE   256
#define MM   512
#define VV   10000
#define GP   0.1f
#define GN   0.1f
#define EPSB 1e-5f
#define EPSL 1e-5f

// Workspace layout (floats), total 47417344 floats = 190 MB.
// m occupies [0, 33554432); semb and vbuf ALIAS its head (dead pre-scan).
// r10/r11 post-mortem: every m store is evicted to EA each pass regardless of
// nt hints (WRITE_SIZE == passes x 128 MiB). k_scan is EA-traffic-bound =>
// the only lever is FEWER m passes. T=2 step-blocking: 1 read + 1 write of m
// per 2 steps, with next-superstep matvecs (vh, G1, G2) fused into the pass.
static constexpr size_t OFF_M    = 0;                        // 128*512*512
static constexpr size_t OFF_SEMB = 0;                        // alias, dead pre-scan
static constexpr size_t OFF_V    = 3276800;                  // alias, dead pre-scan
static constexpr size_t OFF_QEMB = 33554432;                 // 128*256
static constexpr size_t OFF_STAT = OFF_QEMB + 32768;         // 8*256
static constexpr size_t OFF_K    = OFF_STAT + 2048;          // 12800*512 (becomes kn)
static constexpr size_t OFF_V2P  = OFF_K + 6553600;          // 12800*512
static constexpr size_t OFF_W2T  = OFF_V2P + 6553600;        // 512*512
static constexpr size_t OFF_RT   = OFF_W2T + 262144;         // 768*512
static constexpr size_t OFF_VR   = OFF_RT + 393216;          // 128*512

// ---------------------------------------------------------------------------
// K1: embedding accumulation + BN stat partials.
__global__ __launch_bounds__(256) void k_embed(
    const int* __restrict__ story, const int* __restrict__ query,
    const float* __restrict__ we, const float* __restrict__ pos,
    float* __restrict__ semb, float* __restrict__ qemb, float* __restrict__ stats)
{
    int e = threadIdx.x;
    int bid = blockIdx.x;
    float pw[WW];
#pragma unroll
    for (int w = 0; w < WW; ++w) pw[w] = pos[w * EE + e];

    if (bid < 512) {
        int b = bid >> 2;
        int s0 = (bid & 3) * 25;
        float sum = 0.f, sq = 0.f;
        for (int s = s0; s < s0 + 25; ++s) {
            const int* idx = story + (b * SS + s) * WW;
            float acc = 0.f;
#pragma unroll
            for (int w = 0; w < WW; ++w) {
                int t = idx[w];
                acc = fmaf(we[(size_t)t * EE + e], pw[w], acc);
            }
            semb[(size_t)(b * SS + s) * EE + e] = acc;
            sum += acc;
            sq = fmaf(acc, acc, sq);
        }
        atomicAdd(&stats[0 * EE + e], sum);
        atomicAdd(&stats[1 * EE + e], sq);
    } else {
        int b = bid - 512;
        const int* idx = query + b * WW;
        float acc = 0.f;
#pragma unroll
        for (int w = 0; w < WW; ++w) {
            int t = idx[w];
            acc = fmaf(we[(size_t)t * EE + e], pw[w], acc);
        }
        qemb[b * EE + e] = acc;
        atomicAdd(&stats[2 * EE + e], acc);
        atomicAdd(&stats[3 * EE + e], acc * acc);
    }
}

// ---------------------------------------------------------------------------
// K2: finalize BN scale/shift; normalize query embedding in place
__global__ __launch_bounds__(256) void k_finalize(
    float* __restrict__ stats, float* __restrict__ qemb,
    const float* __restrict__ gs, const float* __restrict__ bs,
    const float* __restrict__ gq, const float* __restrict__ bq)
{
    int e = threadIdx.x;
    float ns = (float)(BB * SS);
    float mu = stats[0 * EE + e] / ns;
    float var = stats[1 * EE + e] / ns - mu * mu;
    float sc = rsqrtf(var + EPSB) * gs[e];
    stats[4 * EE + e] = sc;
    stats[5 * EE + e] = bs[e] - mu * sc;

    float nq = (float)BB;
    float muq = stats[2 * EE + e] / nq;
    float varq = stats[3 * EE + e] / nq - muq * muq;
    float scq = rsqrtf(varq + EPSB) * gq[e];
    float shq = bq[e] - muq * scq;
    for (int b = 0; b < BB; ++b) {
        qemb[b * EE + e] = fmaf(qemb[b * EE + e], scq, shq);
    }
}

// ---------------------------------------------------------------------------
// K3: LDS-tiled transposes (coalesced both sides; 32x33 pad).
__global__ __launch_bounds__(256) void k_transpose(
    const float* __restrict__ wW, const float* __restrict__ rW,
    float* __restrict__ w2t, float* __restrict__ rt)
{
    __shared__ float tile[32][33];
    int tid = threadIdx.x;
    int c = tid & 31, r8 = tid >> 5;
    int b = blockIdx.x;
    if (b < 256) {
        int kt = b >> 4, jt = b & 15;
        int j0 = jt * 32, k0 = kt * 32;
#pragma unroll
        for (int rr = 0; rr < 4; ++rr) {
            int r = r8 + rr * 8;
            tile[r][c] = wW[(size_t)(j0 + r) * 1024 + 512 + k0 + c];
        }
        __syncthreads();
#pragma unroll
        for (int rr = 0; rr < 4; ++rr) {
            int r = r8 + rr * 8;
            w2t[(size_t)(k0 + r) * 512 + j0 + c] = tile[c][r];
        }
    } else {
        int idx = b - 256;
        int kt = idx >> 4, jt = idx & 15;
        int j0 = jt * 32, k0 = kt * 32;
#pragma unroll
        for (int rr = 0; rr < 4; ++rr) {
            int r = r8 + rr * 8;
            tile[r][c] = rW[(size_t)(j0 + r) * 768 + k0 + c];
        }
        __syncthreads();
#pragma unroll
        for (int rr = 0; rr < 4; ++rr) {
            int r = r8 + rr * 8;
            rt[(size_t)(k0 + r) * 512 + j0 + c] = tile[c][r];
        }
    }
}

// ---------------------------------------------------------------------------
// K4: k/v GEMM with fused BN on A-load and relu+bias epilogue.
__global__ __launch_bounds__(256) void k_kv(
    const float* __restrict__ semb, const float* __restrict__ stats,
    const float* __restrict__ Wk, const float* __restrict__ bk,
    const float* __restrict__ Wv, const float* __restrict__ bv,
    float* __restrict__ kout, float* __restrict__ vout)
{
    __shared__ float A[64][65];
    __shared__ float WK[64][65];
    __shared__ float WVs[64][65];
    int r0 = blockIdx.x * 64, c0 = blockIdx.y * 64;
    int tid = threadIdx.x;
    int tx = tid & 15, ty = tid >> 4;
    const float* scl = stats + 4 * EE;
    const float* shf = stats + 5 * EE;
    float ak[4][4] = {{0}}, av[4][4] = {{0}};
    for (int kc = 0; kc < 256; kc += 64) {
#pragma unroll
        for (int p = 0; p < 16; ++p) {
            int lin = p * 256 + tid;
            int row = lin >> 6, cc = lin & 63;
            A[row][cc]  = fmaf(semb[(size_t)(r0 + row) * EE + kc + cc], scl[kc + cc], shf[kc + cc]);
            WK[row][cc] = Wk[(size_t)(c0 + row) * EE + kc + cc];
            WVs[row][cc] = Wv[(size_t)(c0 + row) * EE + kc + cc];
        }
        __syncthreads();
        for (int kk = 0; kk < 64; ++kk) {
            float a[4], wk[4], wv[4];
#pragma unroll
            for (int q = 0; q < 4; ++q) {
                a[q] = A[ty * 4 + q][kk];
                wk[q] = WK[tx * 4 + q][kk];
                wv[q] = WVs[tx * 4 + q][kk];
            }
#pragma unroll
            for (int r = 0; r < 4; ++r)
#pragma unroll
                for (int c = 0; c < 4; ++c) {
                    ak[r][c] = fmaf(a[r], wk[c], ak[r][c]);
                    av[r][c] = fmaf(a[r], wv[c], av[r][c]);
                }
        }
        __syncthreads();
    }
#pragma unroll
    for (int r = 0; r < 4; ++r) {
        int row = r0 + ty * 4 + r;
#pragma unroll
        for (int c = 0; c < 4; ++c) {
            int col = c0 + tx * 4 + c;
            kout[(size_t)row * MM + col] = fmaxf(ak[r][c] + bk[col], 0.f);
            vout[(size_t)row * MM + col] = fmaxf(av[r][c] + bv[col], 0.f);
        }
    }
}

// ---------------------------------------------------------------------------
// K5: row LayerNorm in place over k buffer -> kn. Fused (sum,sumsq) butterfly.
__global__ __launch_bounds__(256) void k_rowln(
    float* __restrict__ kbuf, const float* __restrict__ g, const float* __restrict__ bt)
{
    int row = blockIdx.x * 4 + (threadIdx.x >> 6);
    int lane = threadIdx.x & 63;
    float4* kr = (float4*)(kbuf + (size_t)row * MM);
    float4 x0 = kr[lane], x1 = kr[lane + 64];
    float s  = x0.x + x0.y + x0.z + x0.w + x1.x + x1.y + x1.z + x1.w;
    float s2 = x0.x * x0.x + x0.y * x0.y + x0.z * x0.z + x0.w * x0.w +
               x1.x * x1.x + x1.y * x1.y + x1.z * x1.z + x1.w * x1.w;
#pragma unroll
    for (int off = 32; off; off >>= 1) {
        s  += __shfl_down(s, off);
        s2 += __shfl_down(s2, off);
    }
    s = __shfl(s, 0);
    s2 = __shfl(s2, 0);
    float mean = s * (1.f / 512.f);
    float var = s2 * (1.f / 512.f) - mean * mean;
    float rstd = rsqrtf(var + EPSL);
    const float4* g4 = (const float4*)g;
    const float4* b4 = (const float4*)bt;
    float4 ga = g4[lane], gb = g4[lane + 64];
    float4 ba = b4[lane], bb = b4[lane + 64];
    float4 y0, y1;
    y0.x = fmaf((x0.x - mean) * rstd, ga.x, ba.x); y0.y = fmaf((x0.y - mean) * rstd, ga.y, ba.y);
    y0.z = fmaf((x0.z - mean) * rstd, ga.z, ba.z); y0.w = fmaf((x0.w - mean) * rstd, ga.w, ba.w);
    y1.x = fmaf((x1.x - mean) * rstd, gb.x, bb.x); y1.y = fmaf((x1.y - mean) * rstd, gb.y, bb.y);
    y1.z = fmaf((x1.z - mean) * rstd, gb.z, bb.z); y1.w = fmaf((x1.w - mean) * rstd, gb.w, bb.w);
    kr[lane] = y0;
    kr[lane + 64] = y1;
}

// ---------------------------------------------------------------------------
// K6: v2_pre = v @ W1^T + write_b.
__global__ __launch_bounds__(256) void k_v2p(
    const float* __restrict__ v, const float* __restrict__ wW,
    const float* __restrict__ wb, float* __restrict__ out)
{
    __shared__ float A[64][65];
    __shared__ float Wl[64][65];
    int r0 = blockIdx.x * 64, c0 = blockIdx.y * 64;
    int tid = threadIdx.x;
    int tx = tid & 15, ty = tid >> 4;
    float acc[4][4] = {{0}};
    for (int kc = 0; kc < 512; kc += 64) {
#pragma unroll
        for (int p = 0; p < 16; ++p) {
            int lin = p * 256 + tid;
            int row = lin >> 6, cc = lin & 63;
            A[row][cc] = v[(size_t)(r0 + row) * MM + kc + cc];
            Wl[row][cc] = wW[(size_t)(c0 + row) * 1024 + kc + cc];
        }
        __syncthreads();
        for (int kk = 0; kk < 64; ++kk) {
            float a[4], w[4];
#pragma unroll
            for (int q = 0; q < 4; ++q) {
                a[q] = A[ty * 4 + q][kk];
                w[q] = Wl[tx * 4 + q][kk];
            }
#pragma unroll
            for (int r = 0; r < 4; ++r)
#pragma unroll
                for (int c = 0; c < 4; ++c)
                    acc[r][c] = fmaf(a[r], w[c], acc[r][c]);
        }
        __syncthreads();
    }
#pragma unroll
    for (int r = 0; r < 4; ++r) {
        int row = r0 + ty * 4 + r;
#pragma unroll
        for (int c = 0; c < 4; ++c) {
            int col = c0 + tx * 4 + c;
            out[(size_t)row * MM + col] = acc[r][c] + wb[col];
        }
    }
}

// ---------------------------------------------------------------------------
// K7: Hebbian scan, T=2 step-blocked. One block per batch, 1024 threads.
// Superstep u processes steps u, u+1 with ONE m pass (1 read + 1 write).
// Entering superstep u (LDS state): vh = kn_u^T m_u; G1 = (kn_{u+1} o d_u)^T m_u;
// G2 = (kn_{u+1} o c_u)^T m_u; sS1 = sum(kn_{u+1} o c_u), where c=GP*kn, d=1-GN*kn^2.
// Serial chain: LN(u) -> w0; vh_{u+1} = G1 - w0*(G2 - S1); LN(u+1) -> w1.
// m-pass: m2 = step(step(m_u,w0),w1); write m2; fused accumulate next-superstep
// vh (kn_{u+2}), G1' (kn_{u+3} o d_{u+2}), G2' (kn_{u+3} o c_{u+2}).
// All weights are kn-only => precomputable. 100 = 50 x 2, no tail.
// Algebra verified against reference update incl. u=0 base case (r12 audit).
__global__ __launch_bounds__(1024) void k_scan(
    const float* __restrict__ kn_g,   // [B,S,512]
    const float* __restrict__ v2p,    // [B,S,512]
    const float* __restrict__ w2t,    // [512,512]
    const float* __restrict__ g2, const float* __restrict__ b2,
    float* __restrict__ m)            // [B,512,512]
{
    __shared__ __align__(16) float4 packA[512];   // {d_u, c_u, d_{u+1}, c_{u+1}}
    __shared__ __align__(16) float4 packB[512];   // {kn_{u+2}, kn_{u+3}*d_{u+2}, kn_{u+3}*c_{u+2}, 0}
    __shared__ __align__(16) float part[8][512];  // matvec partials / vh-acc partials
    __shared__ __align__(16) float gpB[8][512];   // G1' partials
    __shared__ __align__(16) float gpC[8][512];   // G2' partials
    __shared__ __align__(16) float v2s[2][512];
    __shared__ __align__(16) float v2pre[2][512];
    __shared__ __align__(16) float vh[512];
    __shared__ __align__(16) float G1[512];
    __shared__ __align__(16) float G2[512];
    __shared__ __align__(8) float2 red2[8];
    __shared__ float wred[8];
    __shared__ float sS1;

    int b = blockIdx.x;
    int tid = threadIdx.x;
    int jq = tid & 127;
    int j4 = jq * 4;
    int ig = tid >> 7;                   // 0..7
    float* mb = m + (size_t)b * MM * MM;
    const float* knb = kn_g + (size_t)b * SS * MM;
    const float* v2pb = v2p + (size_t)b * SS * MM;

    float g2r = 0.f, b2r = 0.f;
    if (tid < 512) { g2r = g2[tid]; b2r = b2[tid]; }

    // ---- INIT: vh_0 = 0; G = 0; S1 = sum(kn_1 * GP*kn_0); v2pre = v2p[0,1]
    if (tid < 512) { vh[tid] = 0.f; G1[tid] = 0.f; G2[tid] = 0.f; }
    else {
        int i = tid - 512;
        v2pre[0][i] = v2pb[i];
        v2pre[1][i] = v2pb[MM + i];
        float p = GP * knb[i] * knb[MM + i];
#pragma unroll
        for (int off = 32; off; off >>= 1) p += __shfl_down(p, off);
        if ((tid & 63) == 0) wred[(tid >> 6) - 8] = p;
    }
    __syncthreads();
    if (tid == 0) {
        float s = 0.f;
#pragma unroll
        for (int q = 0; q < 8; ++q) s += wred[q];
        sS1 = s;
    }
    __syncthreads();

    for (int u = 0; u < SS; u += 2) {
        // ---- A1: part = W2^T . vh_u  (skip matvec at u==0: vh_0 == 0)
        {
            float4 acc = make_float4(0.f, 0.f, 0.f, 0.f);
            if (u > 0) {
                int k0 = ig * 64;
#pragma unroll 4
                for (int k = k0; k < k0 + 64; ++k) {
                    float vhk = vh[k];
                    float4 w = *(const float4*)(w2t + (size_t)k * 512 + j4);
                    acc.x = fmaf(vhk, w.x, acc.x);
                    acc.y = fmaf(vhk, w.y, acc.y);
                    acc.z = fmaf(vhk, w.z, acc.z);
                    acc.w = fmaf(vhk, w.w, acc.w);
                }
            }
            *(float4*)&part[ig][j4] = acc;
        }
        __syncthreads();
        // ---- B1: tid<512: pre_u + LN butterfly. tid>=512: build packs + S1' partials.
        float pre = 0.f;
        if (tid < 512) {
#pragma unroll
            for (int q = 0; q < 8; ++q) pre += part[q][tid];
            pre += v2pre[0][tid];
            float s = pre, s2 = pre * pre;
#pragma unroll
            for (int off = 32; off; off >>= 1) {
                s  += __shfl_down(s, off);
                s2 += __shfl_down(s2, off);
            }
            if ((tid & 63) == 0) red2[tid >> 6] = make_float2(s, s2);
        } else {
            int i = tid - 512;
            float k0v = knb[(size_t)u * MM + i];
            float k1v = knb[(size_t)(u + 1) * MM + i];
            float k2v = (u + 2 < SS) ? knb[(size_t)(u + 2) * MM + i] : 0.f;
            float k3v = (u + 3 < SS) ? knb[(size_t)(u + 3) * MM + i] : 0.f;
            float c0 = GP * k0v, d0 = 1.f - GN * k0v * k0v;
            float c1 = GP * k1v, d1 = 1.f - GN * k1v * k1v;
            float c2 = GP * k2v, d2 = 1.f - GN * k2v * k2v;
            packA[i] = make_float4(d0, c0, d1, c1);
            packB[i] = make_float4(k2v, k3v * d2, k3v * c2, 0.f);
            float p = k3v * c2;
#pragma unroll
            for (int off = 32; off; off >>= 1) p += __shfl_down(p, off);
            if ((tid & 63) == 0) wred[(tid >> 6) - 8] = p;
        }
        __syncthreads();
        // ---- C1: w0 = LN_u out; vh <- vh_{u+1} = G1 - w0*(G2 - S1)
        if (tid < 512) {
            float ssum = 0.f, sqsum = 0.f;
#pragma unroll
            for (int q = 0; q < 8; ++q) { ssum += red2[q].x; sqsum += red2[q].y; }
            float mean = ssum * (1.f / 512.f);
            float var = sqsum * (1.f / 512.f) - mean * mean;
            float rstd = rsqrtf(var + EPSL);
            float w0 = fmaf((pre - mean) * rstd, g2r, b2r);
            v2s[0][tid] = w0;
            vh[tid] = G1[tid] - w0 * (G2[tid] - sS1);
        }
        __syncthreads();
        // ---- A2: part = W2^T . vh_{u+1}
        {
            float4 acc = make_float4(0.f, 0.f, 0.f, 0.f);
            int k0 = ig * 64;
#pragma unroll 4
            for (int k = k0; k < k0 + 64; ++k) {
                float vhk = vh[k];
                float4 w = *(const float4*)(w2t + (size_t)k * 512 + j4);
                acc.x = fmaf(vhk, w.x, acc.x);
                acc.y = fmaf(vhk, w.y, acc.y);
                acc.z = fmaf(vhk, w.z, acc.z);
                acc.w = fmaf(vhk, w.w, acc.w);
            }
            *(float4*)&part[ig][j4] = acc;
        }
        __syncthreads();
        // ---- B2: pre_{u+1} + LN butterfly; tid>=512 prefetch v2p[u+2]
        if (tid < 512) {
            pre = 0.f;
#pragma unroll
            for (int q = 0; q < 8; ++q) pre += part[q][tid];
            pre += v2pre[1][tid];
            float s = pre, s2 = pre * pre;
#pragma unroll
            for (int off = 32; off; off >>= 1) {
                s  += __shfl_down(s, off);
                s2 += __shfl_down(s2, off);
            }
            if ((tid & 63) == 0) red2[tid >> 6] = make_float2(s, s2);
        } else {
            int i = tid - 512;
            if (u + 2 < SS) v2pre[0][i] = v2pb[(size_t)(u + 2) * MM + i];
        }
        __syncthreads();
        // ---- C2: w1 = LN_{u+1} out; tid>=512 prefetch v2p[u+3]
        if (tid < 512) {
            float ssum = 0.f, sqsum = 0.f;
#pragma unroll
            for (int q = 0; q < 8; ++q) { ssum += red2[q].x; sqsum += red2[q].y; }
            float mean = ssum * (1.f / 512.f);
            float var = sqsum * (1.f / 512.f) - mean * mean;
            float rstd = rsqrtf(var + EPSL);
            v2s[1][tid] = fmaf((pre - mean) * rstd, g2r, b2r);
        } else {
            int i = tid - 512;
            if (u + 3 < SS) v2pre[1][i] = v2pb[(size_t)(u + 3) * MM + i];
        }
        __syncthreads();
        // ---- M: fused m pass. Apply steps u, u+1; write; accumulate
        //      vh_{u+2}, G1', G2' against m_{u+2} while in registers.
        //      unroll 4 (not 8): 1024-thread cap is 128 VGPR; avoid spills.
        {
            float4 w0 = *(const float4*)&v2s[0][j4];
            float4 w1 = *(const float4*)&v2s[1][j4];
            float4 avh = make_float4(0.f, 0.f, 0.f, 0.f);
            float4 ag1 = make_float4(0.f, 0.f, 0.f, 0.f);
            float4 ag2 = make_float4(0.f, 0.f, 0.f, 0.f);
            if (u == 0) {
#pragma unroll 4
                for (int i = ig; i < 512; i += 8) {
                    float4 pA = packA[i];
                    float4 pB = packB[i];
                    float4 m2v;
                    {
                        float m1 = pA.y * w0.x;
                        float t1 = pA.w * w1.x; m2v.x = fmaf(m1, pA.z - t1, t1);
                    }
                    {
                        float m1 = pA.y * w0.y;
                        float t1 = pA.w * w1.y; m2v.y = fmaf(m1, pA.z - t1, t1);
                    }
                    {
                        float m1 = pA.y * w0.z;
                        float t1 = pA.w * w1.z; m2v.z = fmaf(m1, pA.z - t1, t1);
                    }
                    {
                        float m1 = pA.y * w0.w;
                        float t1 = pA.w * w1.w; m2v.w = fmaf(m1, pA.z - t1, t1);
                    }
                    *(float4*)(mb + (size_t)i * MM + j4) = m2v;
                    avh.x = fmaf(pB.x, m2v.x, avh.x); ag1.x = fmaf(pB.y, m2v.x, ag1.x); ag2.x = fmaf(pB.z, m2v.x, ag2.x);
                    avh.y = fmaf(pB.x, m2v.y, avh.y); ag1.y = fmaf(pB.y, m2v.y, ag1.y); ag2.y = fmaf(pB.z, m2v.y, ag2.y);
                    avh.z = fmaf(pB.x, m2v.z, avh.z); ag1.z = fmaf(pB.y, m2v.z, ag1.z); ag2.z = fmaf(pB.z, m2v.z, ag2.z);
                    avh.w = fmaf(pB.x, m2v.w, avh.w); ag1.w = fmaf(pB.y, m2v.w, ag1.w); ag2.w = fmaf(pB.z, m2v.w, ag2.w);
                }
            } else {
#pragma unroll 4
                for (int i = ig; i < 512; i += 8) {
                    float4 pA = packA[i];
                    float4 pB = packB[i];
                    float4* mp = (float4*)(mb + (size_t)i * MM + j4);
                    float4 mo = *mp;
                    float4 m2v;
                    {
                        float t0 = pA.y * w0.x; float m1 = fmaf(mo.x, pA.x - t0, t0);
                        float t1 = pA.w * w1.x; m2v.x = fmaf(m1, pA.z - t1, t1);
                    }
                    {
                        float t0 = pA.y * w0.y; float m1 = fmaf(mo.y, pA.x - t0, t0);
                        float t1 = pA.w * w1.y; m2v.y = fmaf(m1, pA.z - t1, t1);
                    }
                    {
                        float t0 = pA.y * w0.z; float m1 = fmaf(mo.z, pA.x - t0, t0);
                        float t1 = pA.w * w1.z; m2v.z = fmaf(m1, pA.z - t1, t1);
                    }
                    {
                        float t0 = pA.y * w0.w; float m1 = fmaf(mo.w, pA.x - t0, t0);
                        float t1 = pA.w * w1.w; m2v.w = fmaf(m1, pA.z - t1, t1);
                    }
                    *mp = m2v;
                    avh.x = fmaf(pB.x, m2v.x, avh.x); ag1.x = fmaf(pB.y, m2v.x, ag1.x); ag2.x = fmaf(pB.z, m2v.x, ag2.x);
                    avh.y = fmaf(pB.x, m2v.y, avh.y); ag1.y = fmaf(pB.y, m2v.y, ag1.y); ag2.y = fmaf(pB.z, m2v.y, ag2.y);
                    avh.z = fmaf(pB.x, m2v.z, avh.z); ag1.z = fmaf(pB.y, m2v.z, ag1.z); ag2.z = fmaf(pB.z, m2v.z, ag2.z);
                    avh.w = fmaf(pB.x, m2v.w, avh.w); ag1.w = fmaf(pB.y, m2v.w, ag1.w); ag2.w = fmaf(pB.z, m2v.w, ag2.w);
                }
            }
            *(float4*)&part[ig][j4] = avh;
            *(float4*)&gpB[ig][j4] = ag1;
            *(float4*)&gpC[ig][j4] = ag2;
        }
        __syncthreads();
        // ---- R: reduce partials -> vh, G1, G2; tid 512 finalizes S1'
        if (tid < 512) {
            float sv = 0.f, sg1 = 0.f, sg2 = 0.f;
#pragma unroll
            for (int q = 0; q < 8; ++q) {
                sv  += part[q][tid];
                sg1 += gpB[q][tid];
                sg2 += gpC[q][tid];
            }
            vh[tid] = sv; G1[tid] = sg1; G2[tid] = sg2;
        } else if (tid == 512) {
            float s = 0.f;
#pragma unroll
            for (int q = 0; q < 8; ++q) s += wred[q];
            sS1 = s;
        }
        __syncthreads();
    }
}

// ---------------------------------------------------------------------------
// K8: 3 associative read hops. One block per b, 512 threads.
__global__ __launch_bounds__(512) void k_hops(
    const float* __restrict__ qn, const float* __restrict__ rt,
    const float* __restrict__ rb, const float* __restrict__ m,
    float* __restrict__ vr_out)
{
    __shared__ __align__(16) float q[256];
    __shared__ __align__(16) float vrs[512];
    __shared__ __align__(16) float kr[512];
    __shared__ __align__(16) float part[4][512];
    int b = blockIdx.x, tid = threadIdx.x;
    int jq = tid & 127, j4 = jq * 4, ig = tid >> 7;   // 0..3
    const float* mb = m + (size_t)b * MM * MM;
    if (tid < 256) q[tid] = qn[b * EE + tid];
    vrs[tid] = 0.f;
    __syncthreads();
    for (int hop = 0; hop < 3; ++hop) {
        float4 acc = make_float4(0.f, 0.f, 0.f, 0.f);
#pragma unroll 4
        for (int k = ig * 192; k < ig * 192 + 192; ++k) {
            float x = (k < 256) ? q[k] : vrs[k - 256];
            float4 w = *(const float4*)(rt + (size_t)k * 512 + j4);
            acc.x = fmaf(x, w.x, acc.x);
            acc.y = fmaf(x, w.y, acc.y);
            acc.z = fmaf(x, w.z, acc.z);
            acc.w = fmaf(x, w.w, acc.w);
        }
        *(float4*)&part[ig][j4] = acc;
        __syncthreads();
        {
            float s = rb[tid];
#pragma unroll
            for (int g = 0; g < 4; ++g) s += part[g][tid];
            kr[tid] = s;
        }
        __syncthreads();
        float4 vacc = make_float4(0.f, 0.f, 0.f, 0.f);
#pragma unroll 8
        for (int i = ig; i < 512; i += 4) {
            float ki = kr[i];
            float4 mv = *(const float4*)(mb + (size_t)i * MM + j4);
            vacc.x = fmaf(ki, mv.x, vacc.x);
            vacc.y = fmaf(ki, mv.y, vacc.y);
            vacc.z = fmaf(ki, mv.z, vacc.z);
            vacc.w = fmaf(ki, mv.w, vacc.w);
        }
        *(float4*)&part[ig][j4] = vacc;
        __syncthreads();
        {
            float s = 0.f;
#pragma unroll
            for (int g = 0; g < 4; ++g) s += part[g][tid];
            vrs[tid] = s;
        }
        __syncthreads();
    }
    vr_out[(size_t)b * MM + tid] = vrs[tid];
}

// ---------------------------------------------------------------------------
// K9: logits = vr @ out_W^T + out_b. grid (40 vtiles, 8 btiles), block 256.
__global__ __launch_bounds__(256) void k_out(
    const float* __restrict__ vr, const float* __restrict__ oW,
    const float* __restrict__ ob, float* __restrict__ out)
{
    __shared__ __align__(16) float vs[16][512];
    int v0 = blockIdx.x * 256, b0 = blockIdx.y * 16;
    int tid = threadIdx.x;
    {
        const float4* src = (const float4*)(vr + (size_t)b0 * 512);
        float4* dst = (float4*)&vs[0][0];
#pragma unroll
        for (int p = 0; p < 8; ++p) dst[p * 256 + tid] = src[p * 256 + tid];
    }
    float acc[16];
#pragma unroll
    for (int i = 0; i < 16; ++i) acc[i] = 0.f;
    int v = v0 + tid;
    bool valid = v < VV;
    float bias = valid ? ob[v] : 0.f;
    __syncthreads();
    for (int kc = 0; kc < 512; kc += 16) {
        float4 tmp[4];
        const float4* src = (const float4*)(oW + (size_t)(valid ? v : 0) * 512 + kc);
#pragma unroll
        for (int p = 0; p < 4; ++p) tmp[p] = src[p];
#pragma unroll
        for (int p = 0; p < 4; ++p) {
            float w0 = tmp[p].x, w1 = tmp[p].y, w2 = tmp[p].z, w3 = tmp[p].w;
            int c0 = kc + p * 4;
#pragma unroll
            for (int bb = 0; bb < 16; ++bb) {
                float4 vv = *(const float4*)&vs[bb][c0];
                acc[bb] = fmaf(w0, vv.x, fmaf(w1, vv.y, fmaf(w2, vv.z, fmaf(w3, vv.w, acc[bb]))));
            }
        }
    }
    if (valid) {
#pragma unroll
        for (int bb = 0; bb < 16; ++bb)
            out[(size_t)(b0 + bb) * VV + v] = acc[bb] + bias;
    }
}

// ---------------------------------------------------------------------------
extern "C" void kernel_launch(void* const* d_in, const int* in_sizes, int n_in,
                              void* d_out, int out_size, void* d_ws, size_t ws_size,
                              hipStream_t stream)
{
    const int*   story = (const int*)d_in[0];
    const int*   query = (const int*)d_in[1];
    const float* we    = (const float*)d_in[2];
    const float* pos   = (const float*)d_in[3];
    const float* bsg   = (const float*)d_in[4];
    const float* bsb   = (const float*)d_in[5];
    const float* bqg   = (const float*)d_in[6];
    const float* bqb   = (const float*)d_in[7];
    const float* Wk    = (const float*)d_in[8];
    const float* bk    = (const float*)d_in[9];
    const float* Wv    = (const float*)d_in[10];
    const float* bv    = (const float*)d_in[11];
    const float* wW    = (const float*)d_in[12];
    const float* wb    = (const float*)d_in[13];
    const float* g1    = (const float*)d_in[14];
    const float* b1    = (const float*)d_in[15];
    const float* g2    = (const float*)d_in[16];
    const float* b2    = (const float*)d_in[17];
    const float* rW    = (const float*)d_in[18];
    const float* rb    = (const float*)d_in[19];
    const float* oW    = (const float*)d_in[20];
    const float* ob    = (const float*)d_in[21];

    float* ws   = (float*)d_ws;
    float* mbuf = ws + OFF_M;
    float* semb = ws + OFF_SEMB;   // aliases mbuf head (dead before k_scan)
    float* vbuf = ws + OFF_V;      // aliases mbuf (dead before k_scan)
    float* qemb = ws + OFF_QEMB;
    float* stat = ws + OFF_STAT;
    float* kbuf = ws + OFF_K;      // becomes kn after k_rowln
    float* v2p  = ws + OFF_V2P;
    float* w2t  = ws + OFF_W2T;
    float* rt   = ws + OFF_RT;
    float* vr   = ws + OFF_VR;

    hipMemsetAsync(stat, 0, 4 * EE * sizeof(float), stream);
    k_embed<<<640, 256, 0, stream>>>(story, query, we, pos, semb, qemb, stat);
    k_finalize<<<1, 256, 0, stream>>>(stat, qemb, bsg, bsb, bqg, bqb);
    k_transpose<<<640, 256, 0, stream>>>(wW, rW, w2t, rt);
    k_kv<<<dim3(200, 8), 256, 0, stream>>>(semb, stat, Wk, bk, Wv, bv, kbuf, vbuf);
    k_rowln<<<3200, 256, 0, stream>>>(kbuf, g1, b1);
    k_v2p<<<dim3(200, 8), 256, 0, stream>>>(vbuf, wW, wb, v2p);
    k_scan<<<128, 1024, 0, stream>>>(kbuf, v2p, w2t, g2, b2, mbuf);
    k_hops<<<128, 512, 0, stream>>>(qemb, rt, rb, mbuf, vr);
    k_out<<<dim3(40, 8), 256, 0, stream>>>(vr, oW, ob, (float*)d_out);
}